// Round 7
// baseline (5327.970 us; speedup 1.0000x reference)
//
#include <hip/hip_runtime.h>
#include <cmath>

// Problem dims (fixed by the reference)
constexpr int kB = 32, kH = 48, kT = 24, kS = 256, kA = 64, kR = 8, kF = 1024;
constexpr int kSEQ = kH + 1;           // 49 = history + present step
constexpr float kEPS = 1e-5f;

// Persistent-kernel config: 128 blocks x 512 thr (8 waves).
constexpr int G  = 128;
constexpr int BT = 512;

// Diagnostic knobs (R7: measure primitive costs in-band)
constexpr int kExtraBarriers = 500;    // appended to gru_persist after outputs
constexpr int kPingPongIters = 2000;   // rounds in diag_pingpong

typedef __attribute__((ext_vector_type(8))) short short8;   // 8 x bf16
typedef __attribute__((ext_vector_type(4))) float f32x4;

union U4S8 { uint4 u; short8 s; };

__device__ __forceinline__ unsigned bfbits(float x) {  // RNE f32->bf16
  unsigned u = __float_as_uint(x);
  return (u + 0x7fffu + ((u >> 16) & 1u)) >> 16;
}
__device__ __forceinline__ float bf_lo(unsigned u) { return __uint_as_float(u << 16); }
__device__ __forceinline__ float bf_hi(unsigned u) { return __uint_as_float(u & 0xffff0000u); }
__device__ __forceinline__ float bf2f(unsigned short h) {
  return __uint_as_float(((unsigned)h) << 16);
}
__device__ __forceinline__ float gelu_f(float x) {
  return 0.5f * x * (1.0f + erff(x * 0.7071067811865476f));
}
__device__ __forceinline__ float sigmoid_f(float x) {
  return 1.0f / (1.0f + expf(-x));
}
// dot of 8 bf16 weights (packed) with 8 f32 activations
__device__ __forceinline__ float dot8(const unsigned short* w, const float* y) {
  uint4 u = *(const uint4*)w;
  float r = 0.f;
  r += y[0] * bf_lo(u.x); r += y[1] * bf_hi(u.x);
  r += y[2] * bf_lo(u.y); r += y[3] * bf_hi(u.y);
  r += y[4] * bf_lo(u.z); r += y[5] * bf_hi(u.z);
  r += y[6] * bf_lo(u.w); r += y[7] * bf_hi(u.w);
  return r;
}

// LLC-coherent (L2-bypassing, sc1) relaxed dword ops — no wbl2/buffer_inv.
__device__ __forceinline__ unsigned coh_ld(const unsigned* p) {
  return __hip_atomic_load(p, __ATOMIC_RELAXED, __HIP_MEMORY_SCOPE_AGENT);
}
__device__ __forceinline__ void coh_st(unsigned* p, unsigned v) {
  __hip_atomic_store(p, v, __ATOMIC_RELAXED, __HIP_MEMORY_SCOPE_AGENT);
}

// 16-byte LLC-direct load (sc1). Result must not be consumed before pin8().
__device__ __forceinline__ short8 ld_frag_sc1(const unsigned short* p) {
  short8 d;
  asm volatile("global_load_dwordx4 %0, %1, off sc1" : "=v"(d) : "v"(p));
  return d;
}
__device__ __forceinline__ void pin8(short8& a0, short8& a1, short8& a2, short8& a3,
                                     short8& a4, short8& a5, short8& a6, short8& a7) {
  asm volatile("s_waitcnt vmcnt(0)"
               : "+v"(a0), "+v"(a1), "+v"(a2), "+v"(a3),
                 "+v"(a4), "+v"(a5), "+v"(a6), "+v"(a7)
               :: "memory");
}

// Pinned LLC poll load: bypass L1+L2, explicit drain, no scheduling freedom.
__device__ __forceinline__ unsigned poll_ld(const unsigned* p) {
  unsigned v;
  asm volatile("global_load_dword %0, %1, off sc0 sc1\n\t"
               "s_waitcnt vmcnt(0)"
               : "=v"(v) : "v"(p) : "memory");
  return v;
}

// ---------------- grid-wide barrier: single monotonic counter --------------
__device__ __forceinline__ void grid_barrier(unsigned* cnt, int& gen) {
  __syncthreads();
  if (threadIdx.x == 0) {
    __hip_atomic_fetch_add(cnt, 1u, __ATOMIC_RELAXED, __HIP_MEMORY_SCOPE_AGENT);
    const unsigned target = (unsigned)G * (unsigned)gen;
    while (poll_ld(cnt) < target) { }
  }
  __syncthreads();
  gen++;
}

// ---------------- one GRU layer step via MFMA ------------------------------
template <bool XC>
__device__ __forceinline__ void layer_stage(
    const unsigned short* __restrict__ xsrc,   // [32][1024] bf16
    const unsigned short* __restrict__ hsrc,   // [32][1024] bf16 (always coherent)
    unsigned short* __restrict__ hdst,         // [32][1024] bf16 (coherent stores)
    const short8 (&Bf)[2][3][4],
    float bR, float bZ, float bIN, float bHN,
    float& h_old, float* part, int fb)
{
  const int tid = threadIdx.x;
  const int wv = tid >> 6, l = tid & 63, q = l >> 4, c = l & 15;

  // A fragments: [mat][mtile][kstep]. Issue all loads, then pin once.
  short8 Afr[2][2][4];
  #pragma unroll
  for (int mt = 0; mt < 2; mt++)
    #pragma unroll
    for (int j = 0; j < 4; j++) {
      const int off = (mt*16 + c)*1024 + wv*128 + j*32 + q*8;
      if (XC) Afr[0][mt][j] = ld_frag_sc1(xsrc + off);
      else    Afr[0][mt][j] = *(const short8*)(xsrc + off);
      Afr[1][mt][j] = ld_frag_sc1(hsrc + off);
    }
  if (XC)
    pin8(Afr[0][0][0], Afr[0][0][1], Afr[0][0][2], Afr[0][0][3],
         Afr[0][1][0], Afr[0][1][1], Afr[0][1][2], Afr[0][1][3]);
  pin8(Afr[1][0][0], Afr[1][0][1], Afr[1][0][2], Afr[1][0][3],
       Afr[1][1][0], Afr[1][1][1], Afr[1][1][2], Afr[1][1][3]);

  f32x4 C[4][2];
  #pragma unroll
  for (int s = 0; s < 4; s++)
    #pragma unroll
    for (int mt = 0; mt < 2; mt++)
      C[s][mt] = (f32x4){0.f, 0.f, 0.f, 0.f};

  #pragma unroll
  for (int mt = 0; mt < 2; mt++)
    #pragma unroll
    for (int j = 0; j < 4; j++) {
      C[0][mt] = __builtin_amdgcn_mfma_f32_16x16x32_bf16(Afr[0][mt][j], Bf[0][0][j], C[0][mt], 0, 0, 0);
      C[0][mt] = __builtin_amdgcn_mfma_f32_16x16x32_bf16(Afr[1][mt][j], Bf[1][0][j], C[0][mt], 0, 0, 0);
      C[1][mt] = __builtin_amdgcn_mfma_f32_16x16x32_bf16(Afr[0][mt][j], Bf[0][1][j], C[1][mt], 0, 0, 0);
      C[1][mt] = __builtin_amdgcn_mfma_f32_16x16x32_bf16(Afr[1][mt][j], Bf[1][1][j], C[1][mt], 0, 0, 0);
      C[2][mt] = __builtin_amdgcn_mfma_f32_16x16x32_bf16(Afr[0][mt][j], Bf[0][2][j], C[2][mt], 0, 0, 0);
      C[3][mt] = __builtin_amdgcn_mfma_f32_16x16x32_bf16(Afr[1][mt][j], Bf[1][2][j], C[3][mt], 0, 0, 0);
    }

  // k-slice partials -> LDS (swizzled: 2-way/bank over 64 lanes = free).
  const int perm = (wv + l + (l >> 3)) & 7;
  #pragma unroll
  for (int s = 0; s < 4; s++)
    #pragma unroll
    for (int mt = 0; mt < 2; mt++)
      #pragma unroll
      for (int r = 0; r < 4; r++)
        part[((s*2 + mt)*4 + r)*512 + l*8 + perm] = C[s][mt][r];
  __syncthreads();

  // combine: wave wv -> (mtile = wv&1, reg = wv>>1); lane -> one (b,f)
  const int mt_c = wv & 1, rg = wv >> 1;
  const int b_own = mt_c*16 + q*4 + rg;
  float S[4];
  #pragma unroll
  for (int s = 0; s < 4; s++) {
    const float* pp = part + ((s*2 + mt_c)*4 + rg)*512 + l*8;
    f32x4 a = *(const f32x4*)pp;
    f32x4 b = *(const f32x4*)(pp + 4);
    S[s] = ((a[0]+a[1]) + (a[2]+a[3])) + ((b[0]+b[1]) + (b[2]+b[3]));
  }
  float rr = sigmoid_f(S[0] + bR);
  float zz = sigmoid_f(S[1] + bZ);
  float nn = tanhf(S[2] + bIN + rr * (S[3] + bHN));
  float hn = (1.f - zz)*nn + zz*h_old;
  h_old = hn;
  float nb = __shfl_xor(hn, 1);
  if (!(c & 1)) {
    unsigned pk = bfbits(hn) | (bfbits(nb) << 16);
    coh_st((unsigned*)(hdst + b_own*1024 + fb*16 + c), pk);
  }
  __syncthreads();   // protect smem reuse by next stage
}

// ---------------- fused head + LN + pres + gelu (blocks 0..31, b=blk) ------
__device__ __forceinline__ void f3_stage(
    const unsigned short* __restrict__ y_bf, int t,
    const unsigned short* __restrict__ Ws_bf, const float* __restrict__ b_sout,
    const unsigned short* __restrict__ Wr_bf, const float* __restrict__ b_reward,
    const unsigned short* __restrict__ Wst_bf, const float* __restrict__ b_state,
    const float* __restrict__ g_sn, const float* __restrict__ b_sn,
    const unsigned short* __restrict__ fa_bf,
    float* __restrict__ out_r, float* __restrict__ out_s,
    unsigned short* __restrict__ xbuf_bf, float* part, int b)
{
  const int tid = threadIdx.x;
  float* yb    = part;          // 1024: y in f32
  float* spart = part + 1024;   // 512
  float* s_sh  = part + 1536;   // 256
  float* rpart = part + 1792;   // 64
  float* red1  = part + 2048;   // 512
  float* red2  = part + 2560;   // 512

  {
    unsigned uu = coh_ld((const unsigned*)y_bf + b*512 + tid);
    yb[tid*2]     = bf_lo(uu);
    yb[tid*2 + 1] = bf_hi(uu);
  }
  __syncthreads();
  {  // s partials: j = tid&255, k-half = tid>>8
    const int j = tid & 255, ks = tid >> 8;
    const unsigned short* wr = Ws_bf + j*1024 + ks*512;
    const float* yp = yb + ks*512;
    float acc = 0.f;
    #pragma unroll 8
    for (int k = 0; k < 512; k += 8) acc += dot8(wr + k, yp + k);
    spart[tid] = acc;
  }
  __syncthreads();
  if (tid < 256) {
    float s = spart[tid] + spart[tid + 256] + b_sout[tid];
    out_s[((size_t)b*kT + t)*kS + tid] = s;
    s_sh[tid] = s;
  } else if (tid < 320) {
    const int idx = tid - 256, j = idx >> 3, ks = idx & 7;
    const unsigned short* wr = Wr_bf + j*1024 + ks*128;
    const float* yp = yb + ks*128;
    float acc = 0.f;
    #pragma unroll 4
    for (int k = 0; k < 128; k += 8) acc += dot8(wr + k, yp + k);
    rpart[idx] = acc;
  }
  __syncthreads();
  if (tid < 8) {
    float a = b_reward[tid];
    #pragma unroll
    for (int ks = 0; ks < 8; ks++) a += rpart[tid*8 + ks];
    out_r[((size_t)b*kT + t)*kR + tid] = tanhf(a);
  }
  if (t == kT - 1) return;   // uniform branch: last step needs no next-x
  __syncthreads();
  float uv[2], s1 = 0.f, s2 = 0.f;
  #pragma unroll
  for (int jj = 0; jj < 2; jj++) {
    const int f = tid*2 + jj;
    const unsigned short* wr = Wst_bf + f*256;
    float acc = b_state[f];
    #pragma unroll 8
    for (int k = 0; k < 256; k += 8) acc += dot8(wr + k, s_sh + k);
    uv[jj] = acc; s1 += acc; s2 += acc*acc;
  }
  red1[tid] = s1; red2[tid] = s2;
  __syncthreads();
  for (int off = 256; off > 0; off >>= 1) {
    if (tid < off) { red1[tid] += red1[tid + off]; red2[tid] += red2[tid + off]; }
    __syncthreads();
  }
  const float mean = red1[0] * (1.0f/kF);
  const float var  = red2[0] * (1.0f/kF) - mean*mean;
  const float inv  = rsqrtf(var + kEPS);
  const int f0 = tid*2;
  unsigned fu = *((const unsigned*)(fa_bf + ((size_t)(t+1)*kB + b)*kF) + tid);
  float x0 = (uv[0] - mean)*inv*g_sn[f0]   + b_sn[f0]   + bf_lo(fu);
  float x1 = (uv[1] - mean)*inv*g_sn[f0+1] + b_sn[f0+1] + bf_hi(fu);
  unsigned pk = bfbits(gelu_f(x0)) | (bfbits(gelu_f(x1)) << 16);
  coh_st((unsigned*)xbuf_bf + b*512 + tid, pk);
}

// ---------------- persistent kernel ----------------------------------------
__global__ __launch_bounds__(BT, 2) void gru_persist(
    const float* __restrict__ gru_Wi, const float* __restrict__ gru_Wh,
    const float* __restrict__ gru_bi, const float* __restrict__ gru_bh,
    const unsigned short* __restrict__ Ws_bf, const float* __restrict__ b_sout,
    const unsigned short* __restrict__ Wr_bf, const float* __restrict__ b_reward,
    const unsigned short* __restrict__ Wst_bf, const float* __restrict__ b_state,
    const float* __restrict__ g_sn, const float* __restrict__ b_sn,
    const unsigned short* __restrict__ seq0_bf, const unsigned short* __restrict__ fa_bf,
    unsigned short* h0a, unsigned short* h0b,
    unsigned short* h1a, unsigned short* h1b,
    unsigned short* xbuf_bf,
    unsigned* cnt,
    float* __restrict__ out_r, float* __restrict__ out_s)
{
  __shared__ float part[32 * 512];   // 64 KB, aliased by all stages
  const int tid = threadIdx.x;
  const int blk = blockIdx.x;
  const int wv = tid >> 6, l = tid & 63, q = l >> 4, c = l & 15;
  const bool isL1 = (blk >= 64);
  const int fb = blk & 63;
  const int lay = isL1 ? 1 : 0;

  // ---- preamble: resident B-fragments (bf16) + gate biases ----
  short8 Bf[2][3][4];
  {
    const size_t WLL = (size_t)3 * kF * kF;
    const float* Wm[2] = { gru_Wi + lay*WLL, gru_Wh + lay*WLL };
    #pragma unroll
    for (int m = 0; m < 2; m++)
      #pragma unroll
      for (int g = 0; g < 3; g++)
        #pragma unroll
        for (int j = 0; j < 4; j++) {
          const float* p = Wm[m] + ((size_t)(g*kF + fb*16 + c))*kF + wv*128 + j*32 + q*8;
          float4 a = *(const float4*)p;
          float4 b = *(const float4*)(p + 4);
          U4S8 u;
          u.u.x = bfbits(a.x) | (bfbits(a.y) << 16);
          u.u.y = bfbits(a.z) | (bfbits(a.w) << 16);
          u.u.z = bfbits(b.x) | (bfbits(b.y) << 16);
          u.u.w = bfbits(b.z) | (bfbits(b.w) << 16);
          Bf[m][g][j] = u.s;
        }
  }
  const int f = fb*16 + c;
  const float* bi = gru_bi + lay*3*kF;
  const float* bh = gru_bh + lay*3*kF;
  const float bR  = bi[f] + bh[f];
  const float bZ  = bi[kF + f] + bh[kF + f];
  const float bIN = bi[2*kF + f];
  const float bHN = bh[2*kF + f];

  unsigned short* h0buf[2] = {h0a, h0b};
  unsigned short* h1buf[2] = {h1a, h1b};
  float h_old = 0.f;
  int gen = 1;

  // ---- history wavefront ----
  for (int s = 0; s < 50; s++) {
    if (!isL1) {
      if (s < 49)
        layer_stage<false>(seq0_bf + (size_t)s*kB*kF, h0buf[(s+1)&1], h0buf[s&1],
                           Bf, bR, bZ, bIN, bHN, h_old, part, fb);
    } else {
      if (s >= 1)
        layer_stage<true>(h0buf[(s-1)&1], h1buf[s&1], h1buf[(s-1)&1],
                          Bf, bR, bZ, bIN, bHN, h_old, part, fb);
    }
    grid_barrier(cnt, gen);
  }

  // ---- future ----
  for (int t = 0; t < kT; t++) {
    const int tg = 48 + t;
    if (blk < kB)
      f3_stage(h1buf[tg&1], t, Ws_bf, b_sout, Wr_bf, b_reward,
               Wst_bf, b_state, g_sn, b_sn, fa_bf,
               out_r, out_s, xbuf_bf, part, blk);
    if (t == kT - 1) break;
    grid_barrier(cnt, gen);
    if (!isL1)
      layer_stage<true>(xbuf_bf, h0buf[tg&1], h0buf[(tg+1)&1],
                        Bf, bR, bZ, bIN, bHN, h_old, part, fb);
    grid_barrier(cnt, gen);
    if (isL1)
      layer_stage<true>(h0buf[(tg+1)&1], h1buf[tg&1], h1buf[(tg+1)&1],
                        Bf, bR, bZ, bIN, bHN, h_old, part, fb);
    grid_barrier(cnt, gen);
  }

  // ---- R7 DIAGNOSTIC: 500 pure barriers. t_barrier = (dur - 1577us)/500 ----
  #pragma unroll 1
  for (int e = 0; e < kExtraBarriers; e++) {
    grid_barrier(cnt, gen);
  }
}

// ---------------- R7 DIAGNOSTIC: 2-block sc1 flag ping-pong ----------------
// dur_us / kPingPongIters = one full round (2 cross-block visibility legs).
__global__ __launch_bounds__(64) void diag_pingpong(unsigned* flag) {
  if (threadIdx.x != 0) return;
  if (blockIdx.x == 0) {
    for (unsigned k = 0; k < (unsigned)kPingPongIters; k++) {
      coh_st(flag, 2*k + 1);
      while (poll_ld(flag) < 2*k + 2) { }
    }
  } else if (blockIdx.x == 1) {
    for (unsigned k = 0; k < (unsigned)kPingPongIters; k++) {
      while (poll_ld(flag) < 2*k + 1) { }
      coh_st(flag, 2*k + 2);
    }
  }
}

// ---------------- setup: convert head weights to bf16 ----------------------
__global__ __launch_bounds__(512) void convert_weights(
    const float* __restrict__ ws, unsigned short* __restrict__ o1,
    const float* __restrict__ wst, unsigned short* __restrict__ o2,
    const float* __restrict__ wr, unsigned short* __restrict__ o3)
{
  const int stride = gridDim.x * blockDim.x;
  const int i0 = blockIdx.x * blockDim.x + threadIdx.x;
  for (int i = i0; i < kS*kF; i += stride) o1[i] = (unsigned short)bfbits(ws[i]);
  for (int i = i0; i < kF*kS; i += stride) o2[i] = (unsigned short)bfbits(wst[i]);
  for (int i = i0; i < kR*kF; i += stride) o3[i] = (unsigned short)bfbits(wr[i]);
}

// ---------------- encoder: fa_bf[t][b][f] = bf16(LN(future_a@Wa^T+ba)*g+b) -
__global__ __launch_bounds__(256) void encode_fa_kernel(
    const float* __restrict__ future_a,
    const float* __restrict__ W_action, const float* __restrict__ b_action,
    const float* __restrict__ g_an, const float* __restrict__ b_an,
    unsigned short* __restrict__ fa_bf)
{
  __shared__ __align__(16) float arow[kA];
  __shared__ float red1[256], red2[256];
  const int bid = blockIdx.x;
  const int b = bid & (kB - 1);
  const int t = bid >> 5;
  const int tid = threadIdx.x;
  if (tid < kA) arow[tid] = future_a[((size_t)b*kT + t)*kA + tid];
  __syncthreads();
  float v[4]; float s1 = 0.f, s2 = 0.f;
  #pragma unroll
  for (int j = 0; j < 4; j++) {
    const int ff = tid + j*256;
    const float* wr = W_action + (size_t)ff*kA;
    float acc = b_action[ff];
    for (int k = 0; k < kA; k += 4) {
      float4 w  = *(const float4*)(wr + k);
      float4 xv = *(const float4*)(arow + k);
      acc += xv.x*w.x + xv.y*w.y + xv.z*w.z + xv.w*w.w;
    }
    v[j] = acc; s1 += acc; s2 += acc*acc;
  }
  red1[tid] = s1; red2[tid] = s2;
  __syncthreads();
  for (int off = 128; off > 0; off >>= 1) {
    if (tid < off) { red1[tid] += red1[tid+off]; red2[tid] += red2[tid+off]; }
    __syncthreads();
  }
  const float m = red1[0] * (1.0f/kF);
  const float va = red2[0] * (1.0f/kF) - m*m;
  const float inv = rsqrtf(va + kEPS);
  #pragma unroll
  for (int j = 0; j < 4; j++) {
    const int ff = tid + j*256;
    fa_bf[((size_t)t*kB + b)*kF + ff] =
        (unsigned short)bfbits((v[j] - m)*inv*g_an[ff] + b_an[ff]);
  }
}

// ---------------- encoder: seq0_bf = bf16(gelu(LN_s + LN_a)) ---------------
__global__ __launch_bounds__(256) void encode_seq0_kernel(
    const float* __restrict__ history_s, const float* __restrict__ history_a,
    const float* __restrict__ present_s,
    const float* __restrict__ W_state, const float* __restrict__ b_state,
    const float* __restrict__ g_sn, const float* __restrict__ b_sn,
    const float* __restrict__ W_action, const float* __restrict__ b_action,
    const float* __restrict__ g_an, const float* __restrict__ b_an,
    const unsigned short* __restrict__ fa_bf, unsigned short* __restrict__ seq0_bf)
{
  __shared__ __align__(16) float srow[kS];
  __shared__ __align__(16) float arow[kA];
  __shared__ float red1[256], red2[256];
  const int bid = blockIdx.x;
  const int b = bid & (kB - 1);
  const int t = bid >> 5;                 // 0..48
  const int tid = threadIdx.x;
  const bool hist = (t < kH);
  const float* sp = hist ? (history_s + ((size_t)b*kH + t)*kS)
                         : (present_s + (size_t)b*kS);
  srow[tid] = sp[tid];
  if (hist && tid < kA) arow[tid] = history_a[((size_t)b*kH + t)*kA + tid];
  __syncthreads();

  float u[4]; float s1 = 0.f, s2 = 0.f;
  #pragma unroll
  for (int j = 0; j < 4; j++) {
    const int ff = tid + j*256;
    const float* wr = W_state + (size_t)ff*kS;
    float acc = b_state[ff];
    for (int k = 0; k < kS; k += 4) {
      float4 w  = *(const float4*)(wr + k);
      float4 xv = *(const float4*)(srow + k);
      acc += xv.x*w.x + xv.y*w.y + xv.z*w.z + xv.w*w.w;
    }
    u[j] = acc; s1 += acc; s2 += acc*acc;
  }
  red1[tid] = s1; red2[tid] = s2;
  __syncthreads();
  for (int off = 128; off > 0; off >>= 1) {
    if (tid < off) { red1[tid] += red1[tid+off]; red2[tid] += red2[tid+off]; }
    __syncthreads();
  }
  const float mu = red1[0] * (1.0f/kF);
  const float vu = red2[0] * (1.0f/kF) - mu*mu;
  const float iu = rsqrtf(vu + kEPS);
  __syncthreads();

  if (hist) {
    float v[4]; s1 = 0.f; s2 = 0.f;
    #pragma unroll
    for (int j = 0; j < 4; j++) {
      const int ff = tid + j*256;
      const float* wr = W_action + (size_t)ff*kA;
      float acc = b_action[ff];
      for (int k = 0; k < kA; k += 4) {
        float4 w  = *(const float4*)(wr + k);
        float4 xv = *(const float4*)(arow + k);
        acc += xv.x*w.x + xv.y*w.y + xv.z*w.z + xv.w*w.w;
      }
      v[j] = acc; s1 += acc; s2 += acc*acc;
    }
    red1[tid] = s1; red2[tid] = s2;
    __syncthreads();
    for (int off = 128; off > 0; off >>= 1) {
      if (tid < off) { red1[tid] += red1[tid+off]; red2[tid] += red2[tid+off]; }
      __syncthreads();
    }
    const float mv = red1[0] * (1.0f/kF);
    const float vv = red2[0] * (1.0f/kF) - mv*mv;
    const float iv = rsqrtf(vv + kEPS);
    #pragma unroll
    for (int j = 0; j < 4; j++) {
      const int ff = tid + j*256;
      const float un = (u[j] - mu)*iu*g_sn[ff] + b_sn[ff];
      const float vn = (v[j] - mv)*iv*g_an[ff] + b_an[ff];
      seq0_bf[((size_t)t*kB + b)*kF + ff] = (unsigned short)bfbits(gelu_f(un + vn));
    }
  } else {
    #pragma unroll
    for (int j = 0; j < 4; j++) {
      const int ff = tid + j*256;
      const float un = (u[j] - mu)*iu*g_sn[ff] + b_sn[ff];
      seq0_bf[((size_t)t*kB + b)*kF + ff] =
          (unsigned short)bfbits(gelu_f(un + bf2f(fa_bf[(size_t)b*kF + ff])));
    }
  }
}

// ---------------- host launcher -------------------------------------------
extern "C" void kernel_launch(void* const* d_in, const int* in_sizes, int n_in,
                              void* d_out, int out_size, void* d_ws, size_t ws_size,
                              hipStream_t stream) {
  (void)in_sizes; (void)n_in; (void)out_size;
  const float* history_s = (const float*)d_in[0];
  const float* history_a = (const float*)d_in[1];
  const float* present_s = (const float*)d_in[2];
  const float* future_a  = (const float*)d_in[4];
  const float* W_state   = (const float*)d_in[5];
  const float* b_state   = (const float*)d_in[6];
  const float* g_sn      = (const float*)d_in[7];
  const float* b_sn      = (const float*)d_in[8];
  const float* W_action  = (const float*)d_in[9];
  const float* b_action  = (const float*)d_in[10];
  const float* g_an      = (const float*)d_in[11];
  const float* b_an      = (const float*)d_in[12];
  const float* gru_Wi    = (const float*)d_in[13];
  const float* gru_Wh    = (const float*)d_in[14];
  const float* gru_bi    = (const float*)d_in[15];
  const float* gru_bh    = (const float*)d_in[16];
  const float* W_reward  = (const float*)d_in[17];
  const float* b_reward  = (const float*)d_in[18];
  const float* W_sout    = (const float*)d_in[19];
  const float* b_sout    = (const float*)d_in[20];

  // workspace layout (bytes, 16-aligned)
  char* ws = (char*)d_ws;
  unsigned short* seq0_bf = (unsigned short*)(ws + 0);            // 3,211,264
  unsigned short* fa_bf   = (unsigned short*)(ws + 3211264);      // 1,572,864
  unsigned short* Ws_bf   = (unsigned short*)(ws + 4784128);      //   524,288
  unsigned short* Wst_bf  = (unsigned short*)(ws + 5308416);      //   524,288
  unsigned short* Wr_bf   = (unsigned short*)(ws + 5832704);      //    16,384
  unsigned short* h0a     = (unsigned short*)(ws + 5849088);      //    65,536
  unsigned short* h0b     = (unsigned short*)(ws + 5914624);      //    65,536
  unsigned short* h1a     = (unsigned short*)(ws + 5980160);      //    65,536
  unsigned short* h1b     = (unsigned short*)(ws + 6045696);      //    65,536
  unsigned short* xbuf_bf = (unsigned short*)(ws + 6111232);      //    65,536
  unsigned*       cnt     = (unsigned*)(ws + 6176768);            //       128 (pad line)
  unsigned*       ppflag  = (unsigned*)(ws + 6176896);            //       128 (pad line)
  const size_t need = 6177024;
  if (ws_size < need) return;

  // zero hidden-state buffers + barrier counter + pingpong flag
  hipMemsetAsync((void*)h0a, 0, need - 5849088, stream);

  float* out_r = (float*)d_out;                          // [B][T][R]
  float* out_s = out_r + (size_t)kB*kT*kR;               // [B][T][S]

  hipLaunchKernelGGL(convert_weights, dim3(512), dim3(512), 0, stream,
                     W_sout, Ws_bf, W_state, Wst_bf, W_reward, Wr_bf);
  hipLaunchKernelGGL(encode_fa_kernel, dim3(kT*kB), dim3(256), 0, stream,
                     future_a, W_action, b_action, g_an, b_an, fa_bf);
  hipLaunchKernelGGL(encode_seq0_kernel, dim3(kSEQ*kB), dim3(256), 0, stream,
                     history_s, history_a, present_s,
                     W_state, b_state, g_sn, b_sn,
                     W_action, b_action, g_an, b_an, fa_bf, seq0_bf);
  hipLaunchKernelGGL(gru_persist, dim3(G), dim3(BT), 0, stream,
                     gru_Wi, gru_Wh, gru_bi, gru_bh,
                     Ws_bf, b_sout, Wr_bf, b_reward, Wst_bf, b_state,
                     g_sn, b_sn, seq0_bf, fa_bf,
                     h0a, h0b, h1a, h1b, xbuf_bf, cnt,
                     out_r, out_s);
  hipLaunchKernelGGL(diag_pingpong, dim3(2), dim3(64), 0, stream, ppflag);
}

// Round 8
// 1938.384 us; speedup vs baseline: 2.7487x; 2.7487x over previous
//
#include <hip/hip_runtime.h>
#include <cmath>

// Problem dims (fixed by the reference)
constexpr int kB = 32, kH = 48, kT = 24, kS = 256, kA = 64, kR = 8, kF = 1024;
constexpr int kSEQ = kH + 1;           // 49 = history + present step
constexpr float kEPS = 1e-5f;

// Persistent-kernel config: 128 blocks x 512 thr (8 waves).
// Blocks 0..63: layer-0 f-tiles (16 cols). Blocks 64..127: layer-1.
// Blocks 0..31 also run the fused head stage (one batch each).
constexpr int G  = 128;
constexpr int BT = 512;

typedef __attribute__((ext_vector_type(8))) short short8;   // 8 x bf16
typedef __attribute__((ext_vector_type(4))) float f32x4;

union U4S8 { uint4 u; short8 s; };

__device__ __forceinline__ unsigned bfbits(float x) {  // RNE f32->bf16
  unsigned u = __float_as_uint(x);
  return (u + 0x7fffu + ((u >> 16) & 1u)) >> 16;
}
__device__ __forceinline__ float bf_lo(unsigned u) { return __uint_as_float(u << 16); }
__device__ __forceinline__ float bf_hi(unsigned u) { return __uint_as_float(u & 0xffff0000u); }
__device__ __forceinline__ float bf2f(unsigned short h) {
  return __uint_as_float(((unsigned)h) << 16);
}
__device__ __forceinline__ float gelu_f(float x) {
  return 0.5f * x * (1.0f + erff(x * 0.7071067811865476f));
}
__device__ __forceinline__ float sigmoid_f(float x) {
  return 1.0f / (1.0f + expf(-x));
}
// dot of 8 bf16 weights (packed) with 8 f32 activations
__device__ __forceinline__ float dot8(const unsigned short* w, const float* y) {
  uint4 u = *(const uint4*)w;
  float r = 0.f;
  r += y[0] * bf_lo(u.x); r += y[1] * bf_hi(u.x);
  r += y[2] * bf_lo(u.y); r += y[3] * bf_hi(u.y);
  r += y[4] * bf_lo(u.z); r += y[5] * bf_hi(u.z);
  r += y[6] * bf_lo(u.w); r += y[7] * bf_hi(u.w);
  return r;
}

// sc1 (LLC write-through) store: makes produced data visible to all XCDs
// without any cache-maintenance instructions.
__device__ __forceinline__ void coh_st(unsigned* p, unsigned v) {
  __hip_atomic_store(p, v, __ATOMIC_RELAXED, __HIP_MEMORY_SCOPE_AGENT);
}

// Pinned LLC poll load: bypass L1+L2, explicit drain, no scheduling freedom.
__device__ __forceinline__ unsigned poll_ld(const unsigned* p) {
  unsigned v;
  asm volatile("global_load_dword %0, %1, off sc0 sc1\n\t"
               "s_waitcnt vmcnt(0)"
               : "=v"(v) : "v"(p) : "memory");
  return v;
}

// ---------------- grid-wide barrier: single monotonic counter --------------
// Measured (R7): ~1.95 us per barrier at G=128.
__device__ __forceinline__ void grid_barrier(unsigned* cnt, int& gen) {
  __syncthreads();
  if (threadIdx.x == 0) {
    __hip_atomic_fetch_add(cnt, 1u, __ATOMIC_RELAXED, __HIP_MEMORY_SCOPE_AGENT);
    const unsigned target = (unsigned)G * (unsigned)gen;
    while (poll_ld(cnt) < target) { }
  }
  __syncthreads();
  gen++;
}

// ---------------- one GRU layer step via MFMA ------------------------------
// Block owns 16 f-cols of one layer. Wave wv = k-slice [wv*128, wv*128+128).
// B-frags (weights) resident in VGPRs. Sets: 0=r(i+h), 1=z(i+h), 2=n_i, 3=n_h.
// R8: x/h inputs are PLAIN CACHED loads. Safe because every stage reads a
// buffer address never touched before in this launch (rotation) — the L2
// line must miss and fill from LLC, where producers' sc1 stores landed.
// ~15 of 16 blocks per XCD then hit L2 instead of paying the LLC round trip.
__device__ __forceinline__ void layer_stage(
    const unsigned short* __restrict__ xsrc,   // [32][1024] bf16
    const unsigned short* __restrict__ hsrc,   // [32][1024] bf16
    unsigned short* __restrict__ hdst,         // [32][1024] bf16 (sc1 stores)
    const short8 (&Bf)[2][3][4],
    float bR, float bZ, float bIN, float bHN,
    float& h_old, float* part, int fb)
{
  const int tid = threadIdx.x;
  const int wv = tid >> 6, l = tid & 63, q = l >> 4, c = l & 15;

  // A fragments: [mat][mtile][kstep]
  short8 Afr[2][2][4];
  #pragma unroll
  for (int mt = 0; mt < 2; mt++)
    #pragma unroll
    for (int j = 0; j < 4; j++) {
      const int off = (mt*16 + c)*1024 + wv*128 + j*32 + q*8;
      Afr[0][mt][j] = *(const short8*)(xsrc + off);
      Afr[1][mt][j] = *(const short8*)(hsrc + off);
    }

  f32x4 C[4][2];
  #pragma unroll
  for (int s = 0; s < 4; s++)
    #pragma unroll
    for (int mt = 0; mt < 2; mt++)
      C[s][mt] = (f32x4){0.f, 0.f, 0.f, 0.f};

  #pragma unroll
  for (int mt = 0; mt < 2; mt++)
    #pragma unroll
    for (int j = 0; j < 4; j++) {
      C[0][mt] = __builtin_amdgcn_mfma_f32_16x16x32_bf16(Afr[0][mt][j], Bf[0][0][j], C[0][mt], 0, 0, 0);
      C[0][mt] = __builtin_amdgcn_mfma_f32_16x16x32_bf16(Afr[1][mt][j], Bf[1][0][j], C[0][mt], 0, 0, 0);
      C[1][mt] = __builtin_amdgcn_mfma_f32_16x16x32_bf16(Afr[0][mt][j], Bf[0][1][j], C[1][mt], 0, 0, 0);
      C[1][mt] = __builtin_amdgcn_mfma_f32_16x16x32_bf16(Afr[1][mt][j], Bf[1][1][j], C[1][mt], 0, 0, 0);
      C[2][mt] = __builtin_amdgcn_mfma_f32_16x16x32_bf16(Afr[0][mt][j], Bf[0][2][j], C[2][mt], 0, 0, 0);
      C[3][mt] = __builtin_amdgcn_mfma_f32_16x16x32_bf16(Afr[1][mt][j], Bf[1][2][j], C[3][mt], 0, 0, 0);
    }

  // k-slice partials -> LDS (swizzled: 2-way/bank over 64 lanes = free).
  const int perm = (wv + l + (l >> 3)) & 7;
  #pragma unroll
  for (int s = 0; s < 4; s++)
    #pragma unroll
    for (int mt = 0; mt < 2; mt++)
      #pragma unroll
      for (int r = 0; r < 4; r++)
        part[((s*2 + mt)*4 + r)*512 + l*8 + perm] = C[s][mt][r];
  __syncthreads();

  // combine: wave wv -> (mtile = wv&1, reg = wv>>1); lane -> one (b,f)
  const int mt_c = wv & 1, rg = wv >> 1;
  const int b_own = mt_c*16 + q*4 + rg;
  float S[4];
  #pragma unroll
  for (int s = 0; s < 4; s++) {
    const float* pp = part + ((s*2 + mt_c)*4 + rg)*512 + l*8;
    f32x4 a = *(const f32x4*)pp;
    f32x4 b = *(const f32x4*)(pp + 4);
    S[s] = ((a[0]+a[1]) + (a[2]+a[3])) + ((b[0]+b[1]) + (b[2]+b[3]));
  }
  float rr = sigmoid_f(S[0] + bR);
  float zz = sigmoid_f(S[1] + bZ);
  float nn = tanhf(S[2] + bIN + rr * (S[3] + bHN));
  float hn = (1.f - zz)*nn + zz*h_old;
  h_old = hn;
  // pack lane pairs (c even|odd) into one dword, sc1 store
  float nb = __shfl_xor(hn, 1);
  if (!(c & 1)) {
    unsigned pk = bfbits(hn) | (bfbits(nb) << 16);
    coh_st((unsigned*)(hdst + b_own*1024 + fb*16 + c), pk);
  }
  __syncthreads();   // protect smem reuse by next stage
}

// ---------------- fused head + LN + pres + gelu (blocks 0..31, b=blk) ------
__device__ __forceinline__ void f3_stage(
    const unsigned short* __restrict__ y_bf, int t,
    const unsigned short* __restrict__ Ws_bf, const float* __restrict__ b_sout,
    const unsigned short* __restrict__ Wr_bf, const float* __restrict__ b_reward,
    const unsigned short* __restrict__ Wst_bf, const float* __restrict__ b_state,
    const float* __restrict__ g_sn, const float* __restrict__ b_sn,
    const unsigned short* __restrict__ fa_bf,
    float* __restrict__ out_r, float* __restrict__ out_s,
    unsigned short* __restrict__ xbuf_bf, float* part, int b)
{
  const int tid = threadIdx.x;
  float* yb    = part;          // 1024: y in f32
  float* spart = part + 1024;   // 512
  float* s_sh  = part + 1536;   // 256
  float* rpart = part + 1792;   // 64
  float* red1  = part + 2048;   // 512
  float* red2  = part + 2560;   // 512

  {
    unsigned uu = *((const unsigned*)y_bf + b*512 + tid);   // cached (fresh buf)
    yb[tid*2]     = bf_lo(uu);
    yb[tid*2 + 1] = bf_hi(uu);
  }
  __syncthreads();
  {  // s partials: j = tid&255, k-half = tid>>8
    const int j = tid & 255, ks = tid >> 8;
    const unsigned short* wr = Ws_bf + j*1024 + ks*512;
    const float* yp = yb + ks*512;
    float acc = 0.f;
    #pragma unroll 8
    for (int k = 0; k < 512; k += 8) acc += dot8(wr + k, yp + k);
    spart[tid] = acc;
  }
  __syncthreads();
  if (tid < 256) {
    float s = spart[tid] + spart[tid + 256] + b_sout[tid];
    out_s[((size_t)b*kT + t)*kS + tid] = s;
    s_sh[tid] = s;
  } else if (tid < 320) {
    const int idx = tid - 256, j = idx >> 3, ks = idx & 7;
    const unsigned short* wr = Wr_bf + j*1024 + ks*128;
    const float* yp = yb + ks*128;
    float acc = 0.f;
    #pragma unroll 4
    for (int k = 0; k < 128; k += 8) acc += dot8(wr + k, yp + k);
    rpart[idx] = acc;
  }
  __syncthreads();
  if (tid < 8) {
    float a = b_reward[tid];
    #pragma unroll
    for (int ks = 0; ks < 8; ks++) a += rpart[tid*8 + ks];
    out_r[((size_t)b*kT + t)*kR + tid] = tanhf(a);
  }
  if (t == kT - 1) return;   // uniform branch: last step needs no next-x
  __syncthreads();
  // u[f] = b_state[f] + W_state[f,:] @ s ; LN over 1024; x = gelu(LN + fa[t+1])
  float uv[2], s1 = 0.f, s2 = 0.f;
  #pragma unroll
  for (int jj = 0; jj < 2; jj++) {
    const int f = tid*2 + jj;
    const unsigned short* wr = Wst_bf + f*256;
    float acc = b_state[f];
    #pragma unroll 8
    for (int k = 0; k < 256; k += 8) acc += dot8(wr + k, s_sh + k);
    uv[jj] = acc; s1 += acc; s2 += acc*acc;
  }
  red1[tid] = s1; red2[tid] = s2;
  __syncthreads();
  for (int off = 256; off > 0; off >>= 1) {
    if (tid < off) { red1[tid] += red1[tid + off]; red2[tid] += red2[tid + off]; }
    __syncthreads();
  }
  const float mean = red1[0] * (1.0f/kF);
  const float var  = red2[0] * (1.0f/kF) - mean*mean;
  const float inv  = rsqrtf(var + kEPS);
  const int f0 = tid*2;
  unsigned fu = *((const unsigned*)(fa_bf + ((size_t)(t+1)*kB + b)*kF) + tid);
  float x0 = (uv[0] - mean)*inv*g_sn[f0]   + b_sn[f0]   + bf_lo(fu);
  float x1 = (uv[1] - mean)*inv*g_sn[f0+1] + b_sn[f0+1] + bf_hi(fu);
  unsigned pk = bfbits(gelu_f(x0)) | (bfbits(gelu_f(x1)) << 16);
  coh_st((unsigned*)xbuf_bf + b*512 + tid, pk);
}

// ---------------- persistent kernel ----------------------------------------
// Buffer rotation: h0pool/h1pool hold 73 distinct [32][1024] bf16 buffers
// (50 history + 23 future), xbpool holds 23. No buffer is ever reused within
// a launch -> plain cached reads are coherent (see layer_stage comment).
__global__ __launch_bounds__(BT, 2) void gru_persist(
    const float* __restrict__ gru_Wi, const float* __restrict__ gru_Wh,
    const float* __restrict__ gru_bi, const float* __restrict__ gru_bh,
    const unsigned short* __restrict__ Ws_bf, const float* __restrict__ b_sout,
    const unsigned short* __restrict__ Wr_bf, const float* __restrict__ b_reward,
    const unsigned short* __restrict__ Wst_bf, const float* __restrict__ b_state,
    const float* __restrict__ g_sn, const float* __restrict__ b_sn,
    const unsigned short* __restrict__ seq0_bf, const unsigned short* __restrict__ fa_bf,
    unsigned short* h0pool, unsigned short* h1pool, unsigned short* xbpool,
    unsigned* cnt,
    float* __restrict__ out_r, float* __restrict__ out_s)
{
  __shared__ float part[32 * 512];   // 64 KB, aliased by all stages
  const int tid = threadIdx.x;
  const int blk = blockIdx.x;
  const int wv = tid >> 6, l = tid & 63, q = l >> 4, c = l & 15;
  const bool isL1 = (blk >= 64);
  const int fb = blk & 63;
  const int lay = isL1 ? 1 : 0;
  const size_t BF = (size_t)kB * kF;

  // ---- preamble: resident B-fragments (bf16) + gate biases ----
  short8 Bf[2][3][4];
  {
    const size_t WLL = (size_t)3 * kF * kF;
    const float* Wm[2] = { gru_Wi + lay*WLL, gru_Wh + lay*WLL };
    #pragma unroll
    for (int m = 0; m < 2; m++)
      #pragma unroll
      for (int g = 0; g < 3; g++)
        #pragma unroll
        for (int j = 0; j < 4; j++) {
          const float* p = Wm[m] + ((size_t)(g*kF + fb*16 + c))*kF + wv*128 + j*32 + q*8;
          float4 a = *(const float4*)p;
          float4 b = *(const float4*)(p + 4);
          U4S8 u;
          u.u.x = bfbits(a.x) | (bfbits(a.y) << 16);
          u.u.y = bfbits(a.z) | (bfbits(a.w) << 16);
          u.u.z = bfbits(b.x) | (bfbits(b.y) << 16);
          u.u.w = bfbits(b.z) | (bfbits(b.w) << 16);
          Bf[m][g][j] = u.s;
        }
  }
  const int f = fb*16 + c;
  const float* bi = gru_bi + lay*3*kF;
  const float* bh = gru_bh + lay*3*kF;
  const float bR  = bi[f] + bh[f];
  const float bZ  = bi[kF + f] + bh[kF + f];
  const float bIN = bi[2*kF + f];
  const float bHN = bh[2*kF + f];

  float h_old = 0.f;
  int gen = 1;

  // h0p(i): buffer i in the h0 rotation (i=0 is the zeroed initial state).
  #define H0P(i) (h0pool + (size_t)(i)*BF)
  #define H1P(i) (h1pool + (size_t)(i)*BF)
  #define XBP(i) (xbpool + (size_t)(i)*BF)

  // ---- history wavefront: superstage s = 0..49 ----
  // L0 at s (s<49): x=seq0[s],   h=h0p(s)   -> h0p(s+1)
  // L1 at s (s>=1): x=h0p(s),    h=h1p(s-1) -> h1p(s)
  for (int s = 0; s < 50; s++) {
    if (!isL1) {
      if (s < 49)
        layer_stage(seq0_bf + (size_t)s*BF, H0P(s), H0P(s+1),
                    Bf, bR, bZ, bIN, bHN, h_old, part, fb);
    } else {
      if (s >= 1)
        layer_stage(H0P(s), H1P(s-1), H1P(s),
                    Bf, bR, bZ, bIN, bHN, h_old, part, fb);
    }
    grid_barrier(cnt, gen);
  }

  // ---- future: per t: F3 -> L0 -> L1 (serial feedback chain) ----
  // F3 at t: y=h1p(49+t), writes xbp(t) (t<23)
  // L0 at t: x=xbp(t), h=h0p(49+t) -> h0p(50+t)
  // L1 at t: x=h0p(50+t), h=h1p(49+t) -> h1p(50+t)
  for (int t = 0; t < kT; t++) {
    if (blk < kB)
      f3_stage(H1P(49+t), t, Ws_bf, b_sout, Wr_bf, b_reward,
               Wst_bf, b_state, g_sn, b_sn, fa_bf,
               out_r, out_s, XBP(t), part, blk);
    if (t == kT - 1) break;
    grid_barrier(cnt, gen);
    if (!isL1)
      layer_stage(XBP(t), H0P(49+t), H0P(50+t),
                  Bf, bR, bZ, bIN, bHN, h_old, part, fb);
    grid_barrier(cnt, gen);
    if (isL1)
      layer_stage(H0P(50+t), H1P(49+t), H1P(50+t),
                  Bf, bR, bZ, bIN, bHN, h_old, part, fb);
    grid_barrier(cnt, gen);
  }
  #undef H0P
  #undef H1P
  #undef XBP
}

// ---------------- setup: convert head weights to bf16 ----------------------
__global__ __launch_bounds__(512) void convert_weights(
    const float* __restrict__ ws, unsigned short* __restrict__ o1,
    const float* __restrict__ wst, unsigned short* __restrict__ o2,
    const float* __restrict__ wr, unsigned short* __restrict__ o3)
{
  const int stride = gridDim.x * blockDim.x;
  const int i0 = blockIdx.x * blockDim.x + threadIdx.x;
  for (int i = i0; i < kS*kF; i += stride) o1[i] = (unsigned short)bfbits(ws[i]);
  for (int i = i0; i < kF*kS; i += stride) o2[i] = (unsigned short)bfbits(wst[i]);
  for (int i = i0; i < kR*kF; i += stride) o3[i] = (unsigned short)bfbits(wr[i]);
}

// ---------------- encoder: fa_bf[t][b][f] = bf16(LN(future_a@Wa^T+ba)*g+b) -
__global__ __launch_bounds__(256) void encode_fa_kernel(
    const float* __restrict__ future_a,
    const float* __restrict__ W_action, const float* __restrict__ b_action,
    const float* __restrict__ g_an, const float* __restrict__ b_an,
    unsigned short* __restrict__ fa_bf)
{
  __shared__ __align__(16) float arow[kA];
  __shared__ float red1[256], red2[256];
  const int bid = blockIdx.x;
  const int b = bid & (kB - 1);
  const int t = bid >> 5;
  const int tid = threadIdx.x;
  if (tid < kA) arow[tid] = future_a[((size_t)b*kT + t)*kA + tid];
  __syncthreads();
  float v[4]; float s1 = 0.f, s2 = 0.f;
  #pragma unroll
  for (int j = 0; j < 4; j++) {
    const int ff = tid + j*256;
    const float* wr = W_action + (size_t)ff*kA;
    float acc = b_action[ff];
    for (int k = 0; k < kA; k += 4) {
      float4 w  = *(const float4*)(wr + k);
      float4 xv = *(const float4*)(arow + k);
      acc += xv.x*w.x + xv.y*w.y + xv.z*w.z + xv.w*w.w;
    }
    v[j] = acc; s1 += acc; s2 += acc*acc;
  }
  red1[tid] = s1; red2[tid] = s2;
  __syncthreads();
  for (int off = 128; off > 0; off >>= 1) {
    if (tid < off) { red1[tid] += red1[tid+off]; red2[tid] += red2[tid+off]; }
    __syncthreads();
  }
  const float m = red1[0] * (1.0f/kF);
  const float va = red2[0] * (1.0f/kF) - m*m;
  const float inv = rsqrtf(va + kEPS);
  #pragma unroll
  for (int j = 0; j < 4; j++) {
    const int ff = tid + j*256;
    fa_bf[((size_t)t*kB + b)*kF + ff] =
        (unsigned short)bfbits((v[j] - m)*inv*g_an[ff] + b_an[ff]);
  }
}

// ---------------- encoder: seq0_bf = bf16(gelu(LN_s + LN_a)) ---------------
__global__ __launch_bounds__(256) void encode_seq0_kernel(
    const float* __restrict__ history_s, const float* __restrict__ history_a,
    const float* __restrict__ present_s,
    const float* __restrict__ W_state, const float* __restrict__ b_state,
    const float* __restrict__ g_sn, const float* __restrict__ b_sn,
    const float* __restrict__ W_action, const float* __restrict__ b_action,
    const float* __restrict__ g_an, const float* __restrict__ b_an,
    const unsigned short* __restrict__ fa_bf, unsigned short* __restrict__ seq0_bf)
{
  __shared__ __align__(16) float srow[kS];
  __shared__ __align__(16) float arow[kA];
  __shared__ float red1[256], red2[256];
  const int bid = blockIdx.x;
  const int b = bid & (kB - 1);
  const int t = bid >> 5;                 // 0..48
  const int tid = threadIdx.x;
  const bool hist = (t < kH);
  const float* sp = hist ? (history_s + ((size_t)b*kH + t)*kS)
                         : (present_s + (size_t)b*kS);
  srow[tid] = sp[tid];
  if (hist && tid < kA) arow[tid] = history_a[((size_t)b*kH + t)*kA + tid];
  __syncthreads();

  float u[4]; float s1 = 0.f, s2 = 0.f;
  #pragma unroll
  for (int j = 0; j < 4; j++) {
    const int ff = tid + j*256;
    const float* wr = W_state + (size_t)ff*kS;
    float acc = b_state[ff];
    for (int k = 0; k < kS; k += 4) {
      float4 w  = *(const float4*)(wr + k);
      float4 xv = *(const float4*)(srow + k);
      acc += xv.x*w.x + xv.y*w.y + xv.z*w.z + xv.w*w.w;
    }
    u[j] = acc; s1 += acc; s2 += acc*acc;
  }
  red1[tid] = s1; red2[tid] = s2;
  __syncthreads();
  for (int off = 128; off > 0; off >>= 1) {
    if (tid < off) { red1[tid] += red1[tid+off]; red2[tid] += red2[tid+off]; }
    __syncthreads();
  }
  const float mu = red1[0] * (1.0f/kF);
  const float vu = red2[0] * (1.0f/kF) - mu*mu;
  const float iu = rsqrtf(vu + kEPS);
  __syncthreads();

  if (hist) {
    float v[4]; s1 = 0.f; s2 = 0.f;
    #pragma unroll
    for (int j = 0; j < 4; j++) {
      const int ff = tid + j*256;
      const float* wr = W_action + (size_t)ff*kA;
      float acc = b_action[ff];
      for (int k = 0; k < kA; k += 4) {
        float4 w  = *(const float4*)(wr + k);
        float4 xv = *(const float4*)(arow + k);
        acc += xv.x*w.x + xv.y*w.y + xv.z*w.z + xv.w*w.w;
      }
      v[j] = acc; s1 += acc; s2 += acc*acc;
    }
    red1[tid] = s1; red2[tid] = s2;
    __syncthreads();
    for (int off = 128; off > 0; off >>= 1) {
      if (tid < off) { red1[tid] += red1[tid+off]; red2[tid] += red2[tid+off]; }
      __syncthreads();
    }
    const float mv = red1[0] * (1.0f/kF);
    const float vv = red2[0] * (1.0f/kF) - mv*mv;
    const float iv = rsqrtf(vv + kEPS);
    #pragma unroll
    for (int j = 0; j < 4; j++) {
      const int ff = tid + j*256;
      const float un = (u[j] - mu)*iu*g_sn[ff] + b_sn[ff];
      const float vn = (v[j] - mv)*iv*g_an[ff] + b_an[ff];
      seq0_bf[((size_t)t*kB + b)*kF + ff] = (unsigned short)bfbits(gelu_f(un + vn));
    }
  } else {
    #pragma unroll
    for (int j = 0; j < 4; j++) {
      const int ff = tid + j*256;
      const float un = (u[j] - mu)*iu*g_sn[ff] + b_sn[ff];
      seq0_bf[((size_t)t*kB + b)*kF + ff] =
          (unsigned short)bfbits(gelu_f(un + bf2f(fa_bf[(size_t)b*kF + ff])));
    }
  }
}

// ---------------- host launcher -------------------------------------------
extern "C" void kernel_launch(void* const* d_in, const int* in_sizes, int n_in,
                              void* d_out, int out_size, void* d_ws, size_t ws_size,
                              hipStream_t stream) {
  (void)in_sizes; (void)n_in; (void)out_size;
  const float* history_s = (const float*)d_in[0];
  const float* history_a = (const float*)d_in[1];
  const float* present_s = (const float*)d_in[2];
  /* d_in[3] future_s: unused by the reference forward */
  const float* future_a  = (const float*)d_in[4];
  const float* W_state   = (const float*)d_in[5];
  const float* b_state   = (const float*)d_in[6];
  const float* g_sn      = (const float*)d_in[7];
  const float* b_sn      = (const float*)d_in[8];
  const float* W_action  = (const float*)d_in[9];
  const float* b_action  = (const float*)d_in[10];
  const float* g_an      = (const float*)d_in[11];
  const float* b_an      = (const float*)d_in[12];
  const float* gru_Wi    = (const float*)d_in[13];
  const float* gru_Wh    = (const float*)d_in[14];
  const float* gru_bi    = (const float*)d_in[15];
  const float* gru_bh    = (const float*)d_in[16];
  const float* W_reward  = (const float*)d_in[17];
  const float* b_reward  = (const float*)d_in[18];
  const float* W_sout    = (const float*)d_in[19];
  const float* b_sout    = (const float*)d_in[20];

  // workspace layout (bytes, 16-aligned). Rotation pools: 73+73 h buffers
  // (64 KB each) + 23 xbuf buffers. Total ~16.9 MB.
  char* ws = (char*)d_ws;
  unsigned short* seq0_bf = (unsigned short*)(ws + 0);            //  3,211,264
  unsigned short* fa_bf   = (unsigned short*)(ws + 3211264);      //  1,572,864
  unsigned short* Ws_bf   = (unsigned short*)(ws + 4784128);      //    524,288
  unsigned short* Wst_bf  = (unsigned short*)(ws + 5308416);      //    524,288
  unsigned short* Wr_bf   = (unsigned short*)(ws + 5832704);      //     16,384
  unsigned short* h0pool  = (unsigned short*)(ws + 5849088);      //  4,784,128 (73 x 64K)
  unsigned short* h1pool  = (unsigned short*)(ws + 10633216);     //  4,784,128 (73 x 64K)
  unsigned short* xbpool  = (unsigned short*)(ws + 15417344);     //  1,507,328 (23 x 64K)
  unsigned*       cnt     = (unsigned*)(ws + 16924672);           //        128
  const size_t need = 16924800;
  if (ws_size < need) return;

  // Zero only: initial hidden buffers (index 0 of each pool) + barrier counter.
  // All other pool buffers are fully written before first read.
  hipMemsetAsync((void*)h0pool, 0, 65536, stream);
  hipMemsetAsync((void*)h1pool, 0, 65536, stream);
  hipMemsetAsync((void*)cnt, 0, 128, stream);

  float* out_r = (float*)d_out;                          // [B][T][R]
  float* out_s = out_r + (size_t)kB*kT*kR;               // [B][T][S]

  hipLaunchKernelGGL(convert_weights, dim3(512), dim3(512), 0, stream,
                     W_sout, Ws_bf, W_state, Wst_bf, W_reward, Wr_bf);
  hipLaunchKernelGGL(encode_fa_kernel, dim3(kT*kB), dim3(256), 0, stream,
                     future_a, W_action, b_action, g_an, b_an, fa_bf);
  hipLaunchKernelGGL(encode_seq0_kernel, dim3(kSEQ*kB), dim3(256), 0, stream,
                     history_s, history_a, present_s,
                     W_state, b_state, g_sn, b_sn,
                     W_action, b_action, g_an, b_an, fa_bf, seq0_bf);
  hipLaunchKernelGGL(gru_persist, dim3(G), dim3(BT), 0, stream,
                     gru_Wi, gru_Wh, gru_bi, gru_bh,
                     Ws_bf, b_sout, Wr_bf, b_reward, Wst_bf, b_state,
                     g_sn, b_sn, seq0_bf, fa_bf,
                     h0pool, h1pool, xbpool, cnt,
                     out_r, out_s);
}